// Round 3
// baseline (743.113 us; speedup 1.0000x reference)
//
#include <hip/hip_runtime.h>
#include <math.h>

// ============================================================================
// MoE FFN (dense, E=8): y = sum_e softmax(x@Wr)[:,e] * (gelu(x@W1_e+b1_e)@W2_e+b2_e)
// T=2048 tokens, D=1024, H=4096, E=8.
// R2: ALL inputs/outputs are FP32 (reference setup_inputs is jnp.float32; the
// "(bf16" in the test label is a hardcoded string — misread in R0/R1; fp32
// buffers read as bf16 fully explain the NaNs).
// Compute path: convert to bf16 (fused into transpose), m97-recipe MFMA GEMMs
// (128x128 tile, BK=32, global_load_lds dwordx4, mfma_f32_16x16x32_bf16,
// fp32 accum), exact erf GELU in epilogue, p_te folded into FC1 epilogue so
// FC2 is one K=32768 GEMM split over experts with fp32 atomics.
// ws tiers: A >=214MB (batched), B >=37.9MB (per-expert), D zero-ws fallback.
// ============================================================================

typedef float f32x4 __attribute__((ext_vector_type(4)));
typedef __bf16 bf16x8 __attribute__((ext_vector_type(8)));

#define GLL16(gp, lp)                                                          \
  __builtin_amdgcn_global_load_lds(                                            \
      (const __attribute__((address_space(1))) void*)(gp),                     \
      (__attribute__((address_space(3))) void*)(lp), 16, 0, 0)

__device__ __forceinline__ float gelu_f(float h) {
  return 0.5f * h * (1.f + erff(h * 0.70710678118654752f));  // exact erf GELU
}

// ---------------------------------------------------------------------------
// Router: logits = x @ rw + rb (all fp32), softmax -> P (fp32 ws, optional)
// and probs_out (fp32, part of d_out). One wave per token.
// ---------------------------------------------------------------------------
__global__ void router_kernel(const float* __restrict__ x,
                              const float* __restrict__ rw,
                              const float* __restrict__ rb,
                              float* __restrict__ P,  // may be null (tier D)
                              float* __restrict__ probs_out)
{
  int gid = blockIdx.x * blockDim.x + threadIdx.x;
  int t = gid >> 6;
  int l = gid & 63;
  const float* xr = x + (size_t)t * 1024;
  float a[8];
#pragma unroll
  for (int e = 0; e < 8; ++e) a[e] = 0.f;
  for (int d = l; d < 1024; d += 64) {
    float xv = xr[d];
    f32x4 w0 = *(const f32x4*)(rw + d * 8);
    f32x4 w1 = *(const f32x4*)(rw + d * 8 + 4);
#pragma unroll
    for (int e = 0; e < 4; ++e) a[e] += xv * w0[e];
#pragma unroll
    for (int e = 0; e < 4; ++e) a[4 + e] += xv * w1[e];
  }
#pragma unroll
  for (int off = 32; off > 0; off >>= 1) {
#pragma unroll
    for (int e = 0; e < 8; ++e) a[e] += __shfl_down(a[e], off);
  }
  if (l == 0) {
#pragma unroll
    for (int e = 0; e < 8; ++e) a[e] += rb[e];
    float m = a[0];
#pragma unroll
    for (int e = 1; e < 8; ++e) m = fmaxf(m, a[e]);
    float s = 0.f;
#pragma unroll
    for (int e = 0; e < 8; ++e) { a[e] = __expf(a[e] - m); s += a[e]; }
    float inv = 1.f / s;
#pragma unroll
    for (int e = 0; e < 8; ++e) {
      float p = a[e] * inv;
      if (P) P[t * 8 + e] = p;
      probs_out[t * 8 + e] = p;
    }
  }
}

// ---------------------------------------------------------------------------
// Convert fp32 -> bf16, row-major (for x). One thread = 8 elems.
// ---------------------------------------------------------------------------
__global__ void cvt_kernel(const float* __restrict__ src,
                           __bf16* __restrict__ dst)
{
  size_t i = ((size_t)blockIdx.x * 256 + threadIdx.x) * 8;
  f32x4 v0 = *(const f32x4*)(src + i);
  f32x4 v1 = *(const f32x4*)(src + i + 4);
  bf16x8 o;
#pragma unroll
  for (int j = 0; j < 4; ++j) o[j] = (__bf16)v0[j];
#pragma unroll
  for (int j = 0; j < 4; ++j) o[4 + j] = (__bf16)v1[j];
  *(bf16x8*)(dst + i) = o;
}

// ---------------------------------------------------------------------------
// Fused transpose+convert: src fp32 [z][R][C] -> dst bf16, dst[(c)*dstLd +
// z*zOff + r]. Coalesced 2B stores across lanes (lane = r); src reads L1-cached.
// ---------------------------------------------------------------------------
__global__ void transconv_kernel(const float* __restrict__ src,
                                 __bf16* __restrict__ dst,
                                 int R, int C, int cChunk,
                                 size_t dstLd, size_t zOff)
{
  size_t bs = (size_t)blockIdx.z * (size_t)R * (size_t)C;
  size_t dzo = (size_t)blockIdx.z * zOff;
  int r = blockIdx.x * 256 + threadIdx.x;
  int c0 = blockIdx.y * cChunk;
  const float* s = src + bs + (size_t)r * C;
  for (int c = c0; c < c0 + cChunk; c += 8) {
    f32x4 v0 = *(const f32x4*)(s + c);
    f32x4 v1 = *(const f32x4*)(s + c + 4);
    float vv[8] = {v0[0], v0[1], v0[2], v0[3], v1[0], v1[1], v1[2], v1[3]};
#pragma unroll
    for (int j = 0; j < 8; ++j)
      dst[(size_t)(c + j) * dstLd + dzo + r] = (__bf16)vv[j];
  }
}

// ---------------------------------------------------------------------------
// MFMA mainloop: C[128x128] += A[128xK] * B[128xK]^T, both k-contiguous rows.
// 256 thr = 4 waves (2x2); per k-iter: 4 GLL16 + 8 ds_read_b128 + 16 MFMA.
// ---------------------------------------------------------------------------
__device__ __forceinline__ void mfma_loop(const __bf16* A, const __bf16* B,
                                          int lda, int ldb, int K,
                                          __bf16* As, __bf16* Bs,
                                          f32x4 acc[4][4])
{
  const int tid = threadIdx.x;
  const int w = tid >> 6, l = tid & 63;
  const int sr = (w << 4) + (l >> 2);   // staged row
  const int sc = (l & 3) << 4;          // byte chunk in 64B row
  const size_t ldaB = (size_t)lda * 2, ldbB = (size_t)ldb * 2;
  const char* Ab = (const char*)A + (size_t)sr * ldaB + sc;
  const char* Bb = (const char*)B + (size_t)sr * ldbB + sc;
  char* AsW = (char*)As + w * 1024;  // wave-uniform base; HW adds lane*16
  char* BsW = (char*)Bs + w * 1024;
  const int wm = w & 1, wn = w >> 1;
  const int fr = ((l & 15) * 32) + ((l >> 4) * 8);  // m*BK + quad*8
  const __bf16* Af = As + wm * 2048 + fr;
  const __bf16* Bf = Bs + wn * 2048 + fr;

  for (int k0 = 0; k0 < K; k0 += 32) {
    __syncthreads();
    const size_t kB = (size_t)k0 * 2;
    GLL16(Ab + kB, AsW);
    GLL16(Ab + kB + 64 * ldaB, AsW + 4096);
    GLL16(Bb + kB, BsW);
    GLL16(Bb + kB + 64 * ldbB, BsW + 4096);
    __syncthreads();
    bf16x8 af[4], bfr[4];
#pragma unroll
    for (int i = 0; i < 4; ++i) af[i] = *(const bf16x8*)(Af + i * 512);
#pragma unroll
    for (int j = 0; j < 4; ++j) bfr[j] = *(const bf16x8*)(Bf + j * 512);
#pragma unroll
    for (int i = 0; i < 4; ++i)
#pragma unroll
      for (int j = 0; j < 4; ++j)
        acc[i][j] = __builtin_amdgcn_mfma_f32_16x16x32_bf16(af[i], bfr[j],
                                                            acc[i][j], 0, 0, 0);
  }
}

// ---------------------------------------------------------------------------
// GEMM1: Hs[t, zcol+h] = P[t,e] * gelu(Xb @ W1T_e^T + b1_e)   (bf16 store)
// ---------------------------------------------------------------------------
__global__ void gemm1_kernel(const __bf16* __restrict__ X,
                             const __bf16* __restrict__ W1T,
                             const float* __restrict__ b1,
                             const float* __restrict__ P,
                             __bf16* __restrict__ Hs,
                             int hs_ld, int e_off, size_t b_zstride)
{
  __shared__ __bf16 As[128 * 32], Bs[128 * 32];
  const int bm = blockIdx.x, bn = blockIdx.y, z = blockIdx.z;
  const int e = z + e_off;
  f32x4 acc[4][4];
  const f32x4 z4 = {0.f, 0.f, 0.f, 0.f};
#pragma unroll
  for (int i = 0; i < 4; ++i)
#pragma unroll
    for (int j = 0; j < 4; ++j) acc[i][j] = z4;

  const __bf16* A = X + (size_t)bm * 128 * 1024;
  const __bf16* B = W1T + (size_t)z * b_zstride + (size_t)bn * 128 * 1024;
  mfma_loop(A, B, 1024, 1024, 1024, As, Bs, acc);

  const int tid = threadIdx.x, w = tid >> 6, l = tid & 63;
  const int wm = w & 1, wn = w >> 1, q = l >> 4, c16 = l & 15;
  const int row0 = bm * 128 + wm * 64 + q * 4;
  const int col0 = bn * 128 + wn * 64 + c16;
  float b1v[4];
#pragma unroll
  for (int j = 0; j < 4; ++j)
    b1v[j] = b1[(size_t)e * 4096 + col0 + j * 16];
  float pv[4][4];
#pragma unroll
  for (int i = 0; i < 4; ++i)
#pragma unroll
    for (int r = 0; r < 4; ++r)
      pv[i][r] = P[(size_t)(row0 + i * 16 + r) * 8 + e];
  const int zcol = (hs_ld == 4096) ? 0 : z * 4096;
#pragma unroll
  for (int i = 0; i < 4; ++i)
#pragma unroll
    for (int j = 0; j < 4; ++j)
#pragma unroll
      for (int r = 0; r < 4; ++r) {
        float h = acc[i][j][r] + b1v[j];
        float o = gelu_f(h) * pv[i][r];
        Hs[(size_t)(row0 + i * 16 + r) * hs_ld + zcol + col0 + j * 16] =
            (__bf16)o;
      }
}

// ---------------------------------------------------------------------------
// GEMM2: accb[t,d] += Hs_chunk @ W2T_chunk^T (split-K via z, fp32 atomics)
// ---------------------------------------------------------------------------
__global__ void gemm2_kernel(const __bf16* __restrict__ Hs,
                             const __bf16* __restrict__ W2T,
                             float* __restrict__ accb,
                             int lda, int ldb, int kz)
{
  __shared__ __bf16 As[128 * 32], Bs[128 * 32];
  const int bm = blockIdx.x, bn = blockIdx.y, z = blockIdx.z;
  f32x4 acc[4][4];
  const f32x4 z4 = {0.f, 0.f, 0.f, 0.f};
#pragma unroll
  for (int i = 0; i < 4; ++i)
#pragma unroll
    for (int j = 0; j < 4; ++j) acc[i][j] = z4;

  const __bf16* A = Hs + (size_t)bm * 128 * lda + (size_t)z * kz;
  const __bf16* B = W2T + (size_t)bn * 128 * ldb + (size_t)z * kz;
  mfma_loop(A, B, lda, ldb, 4096, As, Bs, acc);

  const int tid = threadIdx.x, w = tid >> 6, l = tid & 63;
  const int wm = w & 1, wn = w >> 1, q = l >> 4, c16 = l & 15;
  const int row0 = bm * 128 + wm * 64 + q * 4;
  const int col0 = bn * 128 + wn * 64 + c16;
#pragma unroll
  for (int i = 0; i < 4; ++i)
#pragma unroll
    for (int j = 0; j < 4; ++j)
#pragma unroll
      for (int r = 0; r < 4; ++r)
        unsafeAtomicAdd(
            accb + (size_t)(row0 + i * 16 + r) * 1024 + col0 + j * 16,
            acc[i][j][r]);
}

// ---------------------------------------------------------------------------
// Finalize: y = accb + sum_e P*b2   (all fp32)
// ---------------------------------------------------------------------------
__global__ void finalize_kernel(const float* __restrict__ accb,
                                const float* __restrict__ P,
                                const float* __restrict__ b2,
                                float* __restrict__ y)
{
  int idx = blockIdx.x * 256 + threadIdx.x;
  int t = idx >> 8;
  int d0 = (idx & 255) << 2;
  f32x4 a = *(const f32x4*)(accb + (size_t)t * 1024 + d0);
#pragma unroll
  for (int e = 0; e < 8; ++e) {
    float p = P[t * 8 + e];
    f32x4 b = *(const f32x4*)(b2 + (size_t)e * 1024 + d0);
#pragma unroll
    for (int c = 0; c < 4; ++c) a[c] += p * b[c];
  }
  *(f32x4*)(y + (size_t)t * 1024 + d0) = a;
}

// ---------------------------------------------------------------------------
// Tier D: zero-workspace fused VALU fallback (fp32). 8 tokens/block, grid 256.
// ---------------------------------------------------------------------------
__global__ __launch_bounds__(256) void fused_naive_kernel(
    const float* __restrict__ x, const float* __restrict__ w1,
    const float* __restrict__ b1, const float* __restrict__ w2,
    const float* __restrict__ b2, const float* __restrict__ probs,
    float* __restrict__ y)
{
  __shared__ float xs[8][1024];  // 32 KB
  __shared__ float gs[8][64];    // 2 KB
  __shared__ float ps[8];
  const int tid = threadIdx.x;
  const int t0 = blockIdx.x * 8;
  const size_t DH = (size_t)1024 * 4096;
  const int tt = tid >> 5;
  const int d0 = (tid & 31) * 32;
  float acc[32];
#pragma unroll
  for (int i = 0; i < 32; ++i) acc[i] = 0.f;
  {
    const f32x4* xsrc = (const f32x4*)(x + (size_t)t0 * 1024);
    f32x4* xdst = (f32x4*)&xs[0][0];
    for (int i = tid; i < 2048; i += 256) xdst[i] = xsrc[i];
  }
  const int wv = tid >> 6;
  const int hl = tid & 63;
  for (int e = 0; e < 8; ++e) {
    if (tid < 8) ps[tid] = probs[(size_t)(t0 + tid) * 8 + e];
    __syncthreads();
    for (int hc = 0; hc < 4096; hc += 64) {
      float a0 = 0.f, a1 = 0.f;
      const float* w1p = w1 + (size_t)e * DH + hc + hl;
      for (int d = 0; d < 1024; ++d) {
        float wvv = w1p[(size_t)d * 4096];
        a0 += xs[wv * 2 + 0][d] * wvv;
        a1 += xs[wv * 2 + 1][d] * wvv;
      }
      __syncthreads();
      gs[wv * 2 + 0][hl] =
          ps[wv * 2 + 0] * gelu_f(a0 + b1[(size_t)e * 4096 + hc + hl]);
      gs[wv * 2 + 1][hl] =
          ps[wv * 2 + 1] * gelu_f(a1 + b1[(size_t)e * 4096 + hc + hl]);
      __syncthreads();
      const float* w2p = w2 + (size_t)e * DH + (size_t)hc * 1024 + d0;
      for (int hh = 0; hh < 64; ++hh) {
        float g = gs[tt][hh];
#pragma unroll
        for (int jb = 0; jb < 8; ++jb) {
          f32x4 w4 = *(const f32x4*)(w2p + (size_t)hh * 1024 + jb * 4);
#pragma unroll
          for (int j2 = 0; j2 < 4; ++j2) acc[jb * 4 + j2] += g * w4[j2];
        }
      }
    }
#pragma unroll
    for (int j = 0; j < 32; ++j)
      acc[j] += ps[tt] * b2[(size_t)e * 1024 + d0 + j];
    __syncthreads();
  }
  float* yp = y + (size_t)(t0 + tt) * 1024 + d0;
#pragma unroll
  for (int jb = 0; jb < 8; ++jb) {
    f32x4 o = {acc[jb * 4], acc[jb * 4 + 1], acc[jb * 4 + 2], acc[jb * 4 + 3]};
    *(f32x4*)(yp + jb * 4) = o;
  }
}

// ---------------------------------------------------------------------------
extern "C" void kernel_launch(void* const* d_in, const int* in_sizes, int n_in,
                              void* d_out, int out_size, void* d_ws,
                              size_t ws_size, hipStream_t stream)
{
  const float* x  = (const float*)d_in[0];  // [2048,1024]
  const float* rw = (const float*)d_in[1];  // [1024,8]
  const float* rb = (const float*)d_in[2];  // [8]
  const float* w1 = (const float*)d_in[3];  // [8,1024,4096]
  const float* b1 = (const float*)d_in[4];  // [8,4096]
  const float* w2 = (const float*)d_in[5];  // [8,4096,1024]
  const float* b2 = (const float*)d_in[6];  // [8,1024]
  float* y = (float*)d_out;                   // [2048,1024]
  float* probs_out = y + (size_t)2048 * 1024; // [2048,8]

  const size_t DH = (size_t)1024 * 4096;
  // ws layout: P (64K) | accb (8M) | xb (4M) | tier buffers
  const size_t BASE = (64 << 10) + (size_t)2048 * 1024 * 4 +
                      (size_t)2048 * 1024 * 2;                  // 12,648,448
  const size_t TA = BASE + 8 * DH * 2 + (size_t)2048 * 32768 * 2;  // 213,975,040
  const size_t TB = BASE + DH * 2 + (size_t)2048 * 4096 * 2;       // 37,814,272

  char* ws = (char*)d_ws;
  float* P = (float*)ws;
  float* accb = (float*)(ws + (64 << 10));
  __bf16* xb = (__bf16*)(ws + (64 << 10) + (size_t)2048 * 1024 * 4);
  char* ws2 = ws + BASE;

  if (ws_size >= TA) {
    router_kernel<<<512, 256, 0, stream>>>(x, rw, rb, P, probs_out);
    hipMemsetAsync(accb, 0, (size_t)2048 * 1024 * 4, stream);
    cvt_kernel<<<1024, 256, 0, stream>>>(x, xb);
    __bf16* WT = (__bf16*)ws2;      // 64 MB: W1T, then reused as W2T
    __bf16* Hs = WT + 8 * DH;       // [2048][32768] bf16
    // W1 [e][1024][4096] -> W1T[e][4096][1024]
    transconv_kernel<<<dim3(4, 64, 8), 256, 0, stream>>>(
        w1, WT, 1024, 4096, 64, 1024, DH);
    gemm1_kernel<<<dim3(16, 32, 8), 256, 0, stream>>>(xb, WT, b1, P, Hs,
                                                      32768, 0, DH);
    // W2 [e][4096][1024] -> W2T[d][e*4096+h], dstLd=32768
    transconv_kernel<<<dim3(16, 16, 8), 256, 0, stream>>>(
        w2, WT, 4096, 1024, 64, 32768, 4096);
    gemm2_kernel<<<dim3(16, 8, 8), 256, 0, stream>>>(Hs, WT, accb, 32768,
                                                     32768, 4096);
    finalize_kernel<<<2048, 256, 0, stream>>>(accb, P, b2, y);
  } else if (ws_size >= TB) {
    router_kernel<<<512, 256, 0, stream>>>(x, rw, rb, P, probs_out);
    hipMemsetAsync(accb, 0, (size_t)2048 * 1024 * 4, stream);
    cvt_kernel<<<1024, 256, 0, stream>>>(x, xb);
    __bf16* WT = (__bf16*)ws2;      // 8 MB
    __bf16* HsE = WT + DH;          // 16 MB
    for (int e = 0; e < 8; ++e) {
      transconv_kernel<<<dim3(4, 64, 1), 256, 0, stream>>>(
          w1 + e * DH, WT, 1024, 4096, 64, 1024, 0);
      gemm1_kernel<<<dim3(16, 32, 1), 256, 0, stream>>>(xb, WT, b1, P, HsE,
                                                        4096, e, 0);
      transconv_kernel<<<dim3(16, 16, 1), 256, 0, stream>>>(
          w2 + e * DH, WT, 4096, 1024, 64, 4096, 0);
      gemm2_kernel<<<dim3(16, 8, 1), 256, 0, stream>>>(HsE, WT, accb, 4096,
                                                       4096, 0);
    }
    finalize_kernel<<<2048, 256, 0, stream>>>(accb, P, b2, y);
  } else {
    // Tier D: zero-ws fused fallback
    router_kernel<<<512, 256, 0, stream>>>(x, rw, rb, (float*)nullptr,
                                           probs_out);
    fused_naive_kernel<<<256, 256, 0, stream>>>(x, w1, b1, w2, b2, probs_out,
                                                y);
  }
}

// Round 4
// 709.423 us; speedup vs baseline: 1.0475x; 1.0475x over previous
//
#include <hip/hip_runtime.h>
#include <math.h>

// ============================================================================
// MoE FFN (dense, E=8): y = sum_e softmax(x@Wr)[:,e] * (gelu(x@W1_e+b1_e)@W2_e+b2_e)
// T=2048, D=1024, H=4096, E=8. FP32 in/out; bf16 MFMA compute.
// R3 -> R4: BK=64 mainloop (32 MFMA per barrier pair, was 16) + XOR-swizzled
// LDS layout for conflict-free b128 fragment reads. 128x128 tile, GLL16
// staging, mfma_f32_16x16x32_bf16, fp32 accum. p_te folded into FC1 epilogue;
// FC2 = one K=32768 GEMM split over experts (z) with fp32 atomics.
// ws tiers: A >=214MB (batched), B >=37.9MB (per-expert), D zero-ws fallback.
// ============================================================================

typedef float f32x4 __attribute__((ext_vector_type(4)));
typedef __bf16 bf16x8 __attribute__((ext_vector_type(8)));

#define GLL16(gp, lp)                                                          \
  __builtin_amdgcn_global_load_lds(                                            \
      (const __attribute__((address_space(1))) void*)(gp),                     \
      (__attribute__((address_space(3))) void*)(lp), 16, 0, 0)

__device__ __forceinline__ float gelu_f(float h) {
  return 0.5f * h * (1.f + erff(h * 0.70710678118654752f));  // exact erf GELU
}

// ---------------------------------------------------------------------------
// Router: logits = x @ rw + rb (fp32), softmax -> P (ws) + probs_out (d_out)
// ---------------------------------------------------------------------------
__global__ void router_kernel(const float* __restrict__ x,
                              const float* __restrict__ rw,
                              const float* __restrict__ rb,
                              float* __restrict__ P,  // may be null (tier D)
                              float* __restrict__ probs_out)
{
  int gid = blockIdx.x * blockDim.x + threadIdx.x;
  int t = gid >> 6;
  int l = gid & 63;
  const float* xr = x + (size_t)t * 1024;
  float a[8];
#pragma unroll
  for (int e = 0; e < 8; ++e) a[e] = 0.f;
  for (int d = l; d < 1024; d += 64) {
    float xv = xr[d];
    f32x4 w0 = *(const f32x4*)(rw + d * 8);
    f32x4 w1 = *(const f32x4*)(rw + d * 8 + 4);
#pragma unroll
    for (int e = 0; e < 4; ++e) a[e] += xv * w0[e];
#pragma unroll
    for (int e = 0; e < 4; ++e) a[4 + e] += xv * w1[e];
  }
#pragma unroll
  for (int off = 32; off > 0; off >>= 1) {
#pragma unroll
    for (int e = 0; e < 8; ++e) a[e] += __shfl_down(a[e], off);
  }
  if (l == 0) {
#pragma unroll
    for (int e = 0; e < 8; ++e) a[e] += rb[e];
    float m = a[0];
#pragma unroll
    for (int e = 1; e < 8; ++e) m = fmaxf(m, a[e]);
    float s = 0.f;
#pragma unroll
    for (int e = 0; e < 8; ++e) { a[e] = __expf(a[e] - m); s += a[e]; }
    float inv = 1.f / s;
#pragma unroll
    for (int e = 0; e < 8; ++e) {
      float p = a[e] * inv;
      if (P) P[t * 8 + e] = p;
      probs_out[t * 8 + e] = p;
    }
  }
}

// ---------------------------------------------------------------------------
// Convert fp32 -> bf16 row-major (for x)
// ---------------------------------------------------------------------------
__global__ void cvt_kernel(const float* __restrict__ src,
                           __bf16* __restrict__ dst)
{
  size_t i = ((size_t)blockIdx.x * 256 + threadIdx.x) * 8;
  f32x4 v0 = *(const f32x4*)(src + i);
  f32x4 v1 = *(const f32x4*)(src + i + 4);
  bf16x8 o;
#pragma unroll
  for (int j = 0; j < 4; ++j) o[j] = (__bf16)v0[j];
#pragma unroll
  for (int j = 0; j < 4; ++j) o[4 + j] = (__bf16)v1[j];
  *(bf16x8*)(dst + i) = o;
}

// ---------------------------------------------------------------------------
// Fused transpose+convert: src fp32 [z][R][C] -> dst bf16 [c][dstLd] + z*zOff + r
// ---------------------------------------------------------------------------
__global__ void transconv_kernel(const float* __restrict__ src,
                                 __bf16* __restrict__ dst,
                                 int R, int C, int cChunk,
                                 size_t dstLd, size_t zOff)
{
  size_t bs = (size_t)blockIdx.z * (size_t)R * (size_t)C;
  size_t dzo = (size_t)blockIdx.z * zOff;
  int r = blockIdx.x * 256 + threadIdx.x;
  int c0 = blockIdx.y * cChunk;
  const float* s = src + bs + (size_t)r * C;
  for (int c = c0; c < c0 + cChunk; c += 8) {
    f32x4 v0 = *(const f32x4*)(s + c);
    f32x4 v1 = *(const f32x4*)(s + c + 4);
    float vv[8] = {v0[0], v0[1], v0[2], v0[3], v1[0], v1[1], v1[2], v1[3]};
#pragma unroll
    for (int j = 0; j < 8; ++j)
      dst[(size_t)(c + j) * dstLd + dzo + r] = (__bf16)vv[j];
  }
}

// ---------------------------------------------------------------------------
// MFMA mainloop, BK=64: C[128x128] += A[128xK] * B[128xK]^T.
// LDS tiles 128 x 64 (128 B/row), XOR-swizzled: chunk c (16B) of row r lives
// at slot c^(r&7). Staging: GLL16 instr g covers rows [8g,8g+8); lane l
// stores LDS slot (l&7) of row 8g+(l>>3), so it SOURCES global chunk
// (l&7)^(l>>3). Per k-iter: 8 GLL16 + 16 ds_read_b128 + 32 MFMA per wave pair.
// ---------------------------------------------------------------------------
__device__ __forceinline__ void mfma_loop(const __bf16* A, const __bf16* B,
                                          int lda, int ldb, int K,
                                          __bf16* As, __bf16* Bs,
                                          f32x4 acc[4][4])
{
  const int tid = threadIdx.x;
  const int w = tid >> 6, l = tid & 63;
  const int rg = l >> 3;                    // row within 8-row group
  const int csrc = ((l & 7) ^ rg) << 4;     // swizzled source byte chunk
  const size_t ldaB = (size_t)lda * 2, ldbB = (size_t)ldb * 2;
  const char* Ab = (const char*)A + (size_t)(w * 32 + rg) * ldaB + csrc;
  const char* Bb = (const char*)B + (size_t)(w * 32 + rg) * ldbB + csrc;
  char* AsW = (char*)As + w * 4096;  // wave's 4 instrs at +i*1024
  char* BsW = (char*)Bs + w * 4096;
  const int wm = w & 1, wn = w >> 1;
  const int m16 = l & 15, quad = l >> 4;
  const int rowA0 = wm * 64 + m16;   // + 16*i
  const int rowB0 = wn * 64 + m16;   // + 16*j
  const int sw = m16 & 7;            // row&7 (16i, 64wm are 0 mod 8)

  for (int k0 = 0; k0 < K; k0 += 64) {
    __syncthreads();
    const size_t kB = (size_t)k0 * 2;
#pragma unroll
    for (int i = 0; i < 4; ++i) {
      GLL16(Ab + kB + (size_t)(8 * i) * ldaB, AsW + i * 1024);
      GLL16(Bb + kB + (size_t)(8 * i) * ldbB, BsW + i * 1024);
    }
    __syncthreads();
#pragma unroll
    for (int kk = 0; kk < 2; ++kk) {
      const int pos = ((quad + 4 * kk) ^ sw) << 3;  // elem offset of chunk
      bf16x8 af[4], bfr[4];
#pragma unroll
      for (int i = 0; i < 4; ++i)
        af[i] = *(const bf16x8*)(As + (rowA0 + 16 * i) * 64 + pos);
#pragma unroll
      for (int j = 0; j < 4; ++j)
        bfr[j] = *(const bf16x8*)(Bs + (rowB0 + 16 * j) * 64 + pos);
#pragma unroll
      for (int i = 0; i < 4; ++i)
#pragma unroll
        for (int j = 0; j < 4; ++j)
          acc[i][j] = __builtin_amdgcn_mfma_f32_16x16x32_bf16(
              af[i], bfr[j], acc[i][j], 0, 0, 0);
    }
  }
}

// ---------------------------------------------------------------------------
// GEMM1: Hs[t, zcol+h] = P[t,e] * gelu(Xb @ W1T_e^T + b1_e)   (bf16 store)
// ---------------------------------------------------------------------------
__global__ void gemm1_kernel(const __bf16* __restrict__ X,
                             const __bf16* __restrict__ W1T,
                             const float* __restrict__ b1,
                             const float* __restrict__ P,
                             __bf16* __restrict__ Hs,
                             int hs_ld, int e_off, size_t b_zstride)
{
  __shared__ __bf16 As[128 * 64], Bs[128 * 64];
  const int bm = blockIdx.x, bn = blockIdx.y, z = blockIdx.z;
  const int e = z + e_off;
  f32x4 acc[4][4];
  const f32x4 z4 = {0.f, 0.f, 0.f, 0.f};
#pragma unroll
  for (int i = 0; i < 4; ++i)
#pragma unroll
    for (int j = 0; j < 4; ++j) acc[i][j] = z4;

  const __bf16* A = X + (size_t)bm * 128 * 1024;
  const __bf16* B = W1T + (size_t)z * b_zstride + (size_t)bn * 128 * 1024;
  mfma_loop(A, B, 1024, 1024, 1024, As, Bs, acc);

  const int tid = threadIdx.x, w = tid >> 6, l = tid & 63;
  const int wm = w & 1, wn = w >> 1, q = l >> 4, c16 = l & 15;
  const int row0 = bm * 128 + wm * 64 + q * 4;
  const int col0 = bn * 128 + wn * 64 + c16;
  float b1v[4];
#pragma unroll
  for (int j = 0; j < 4; ++j)
    b1v[j] = b1[(size_t)e * 4096 + col0 + j * 16];
  float pv[4][4];
#pragma unroll
  for (int i = 0; i < 4; ++i)
#pragma unroll
    for (int r = 0; r < 4; ++r)
      pv[i][r] = P[(size_t)(row0 + i * 16 + r) * 8 + e];
  const int zcol = (hs_ld == 4096) ? 0 : z * 4096;
#pragma unroll
  for (int i = 0; i < 4; ++i)
#pragma unroll
    for (int j = 0; j < 4; ++j)
#pragma unroll
      for (int r = 0; r < 4; ++r) {
        float h = acc[i][j][r] + b1v[j];
        float o = gelu_f(h) * pv[i][r];
        Hs[(size_t)(row0 + i * 16 + r) * hs_ld + zcol + col0 + j * 16] =
            (__bf16)o;
      }
}

// ---------------------------------------------------------------------------
// GEMM2: accb[t,d] += Hs_chunk @ W2T_chunk^T (split-K via z, fp32 atomics)
// ---------------------------------------------------------------------------
__global__ void gemm2_kernel(const __bf16* __restrict__ Hs,
                             const __bf16* __restrict__ W2T,
                             float* __restrict__ accb,
                             int lda, int ldb, int kz)
{
  __shared__ __bf16 As[128 * 64], Bs[128 * 64];
  const int bm = blockIdx.x, bn = blockIdx.y, z = blockIdx.z;
  f32x4 acc[4][4];
  const f32x4 z4 = {0.f, 0.f, 0.f, 0.f};
#pragma unroll
  for (int i = 0; i < 4; ++i)
#pragma unroll
    for (int j = 0; j < 4; ++j) acc[i][j] = z4;

  const __bf16* A = Hs + (size_t)bm * 128 * lda + (size_t)z * kz;
  const __bf16* B = W2T + (size_t)bn * 128 * ldb + (size_t)z * kz;
  mfma_loop(A, B, lda, ldb, 4096, As, Bs, acc);

  const int tid = threadIdx.x, w = tid >> 6, l = tid & 63;
  const int wm = w & 1, wn = w >> 1, q = l >> 4, c16 = l & 15;
  const int row0 = bm * 128 + wm * 64 + q * 4;
  const int col0 = bn * 128 + wn * 64 + c16;
#pragma unroll
  for (int i = 0; i < 4; ++i)
#pragma unroll
    for (int j = 0; j < 4; ++j)
#pragma unroll
      for (int r = 0; r < 4; ++r)
        unsafeAtomicAdd(
            accb + (size_t)(row0 + i * 16 + r) * 1024 + col0 + j * 16,
            acc[i][j][r]);
}

// ---------------------------------------------------------------------------
// Finalize: y = accb + sum_e P*b2   (fp32)
// ---------------------------------------------------------------------------
__global__ void finalize_kernel(const float* __restrict__ accb,
                                const float* __restrict__ P,
                                const float* __restrict__ b2,
                                float* __restrict__ y)
{
  int idx = blockIdx.x * 256 + threadIdx.x;
  int t = idx >> 8;
  int d0 = (idx & 255) << 2;
  f32x4 a = *(const f32x4*)(accb + (size_t)t * 1024 + d0);
#pragma unroll
  for (int e = 0; e < 8; ++e) {
    float p = P[t * 8 + e];
    f32x4 b = *(const f32x4*)(b2 + (size_t)e * 1024 + d0);
#pragma unroll
    for (int c = 0; c < 4; ++c) a[c] += p * b[c];
  }
  *(f32x4*)(y + (size_t)t * 1024 + d0) = a;
}

// ---------------------------------------------------------------------------
// Tier D: zero-workspace fused VALU fallback (fp32)
// ---------------------------------------------------------------------------
__global__ __launch_bounds__(256) void fused_naive_kernel(
    const float* __restrict__ x, const float* __restrict__ w1,
    const float* __restrict__ b1, const float* __restrict__ w2,
    const float* __restrict__ b2, const float* __restrict__ probs,
    float* __restrict__ y)
{
  __shared__ float xs[8][1024];
  __shared__ float gs[8][64];
  __shared__ float ps[8];
  const int tid = threadIdx.x;
  const int t0 = blockIdx.x * 8;
  const size_t DH = (size_t)1024 * 4096;
  const int tt = tid >> 5;
  const int d0 = (tid & 31) * 32;
  float acc[32];
#pragma unroll
  for (int i = 0; i < 32; ++i) acc[i] = 0.f;
  {
    const f32x4* xsrc = (const f32x4*)(x + (size_t)t0 * 1024);
    f32x4* xdst = (f32x4*)&xs[0][0];
    for (int i = tid; i < 2048; i += 256) xdst[i] = xsrc[i];
  }
  const int wv = tid >> 6;
  const int hl = tid & 63;
  for (int e = 0; e < 8; ++e) {
    if (tid < 8) ps[tid] = probs[(size_t)(t0 + tid) * 8 + e];
    __syncthreads();
    for (int hc = 0; hc < 4096; hc += 64) {
      float a0 = 0.f, a1 = 0.f;
      const float* w1p = w1 + (size_t)e * DH + hc + hl;
      for (int d = 0; d < 1024; ++d) {
        float wvv = w1p[(size_t)d * 4096];
        a0 += xs[wv * 2 + 0][d] * wvv;
        a1 += xs[wv * 2 + 1][d] * wvv;
      }
      __syncthreads();
      gs[wv * 2 + 0][hl] =
          ps[wv * 2 + 0] * gelu_f(a0 + b1[(size_t)e * 4096 + hc + hl]);
      gs[wv * 2 + 1][hl] =
          ps[wv * 2 + 1] * gelu_f(a1 + b1[(size_t)e * 4096 + hc + hl]);
      __syncthreads();
      const float* w2p = w2 + (size_t)e * DH + (size_t)hc * 1024 + d0;
      for (int hh = 0; hh < 64; ++hh) {
        float g = gs[tt][hh];
#pragma unroll
        for (int jb = 0; jb < 8; ++jb) {
          f32x4 w4 = *(const f32x4*)(w2p + (size_t)hh * 1024 + jb * 4);
#pragma unroll
          for (int j2 = 0; j2 < 4; ++j2) acc[jb * 4 + j2] += g * w4[j2];
        }
      }
    }
#pragma unroll
    for (int j = 0; j < 32; ++j)
      acc[j] += ps[tt] * b2[(size_t)e * 1024 + d0 + j];
    __syncthreads();
  }
  float* yp = y + (size_t)(t0 + tt) * 1024 + d0;
#pragma unroll
  for (int jb = 0; jb < 8; ++jb) {
    f32x4 o = {acc[jb * 4], acc[jb * 4 + 1], acc[jb * 4 + 2], acc[jb * 4 + 3]};
    *(f32x4*)(yp + jb * 4) = o;
  }
}

// ---------------------------------------------------------------------------
extern "C" void kernel_launch(void* const* d_in, const int* in_sizes, int n_in,
                              void* d_out, int out_size, void* d_ws,
                              size_t ws_size, hipStream_t stream)
{
  const float* x  = (const float*)d_in[0];  // [2048,1024]
  const float* rw = (const float*)d_in[1];  // [1024,8]
  const float* rb = (const float*)d_in[2];  // [8]
  const float* w1 = (const float*)d_in[3];  // [8,1024,4096]
  const float* b1 = (const float*)d_in[4];  // [8,4096]
  const float* w2 = (const float*)d_in[5];  // [8,4096,1024]
  const float* b2 = (const float*)d_in[6];  // [8,1024]
  float* y = (float*)d_out;                   // [2048,1024]
  float* probs_out = y + (size_t)2048 * 1024; // [2048,8]

  const size_t DH = (size_t)1024 * 4096;
  const size_t BASE = (64 << 10) + (size_t)2048 * 1024 * 4 +
                      (size_t)2048 * 1024 * 2;                     // P|accb|xb
  const size_t TA = BASE + 8 * DH * 2 + (size_t)2048 * 32768 * 2;  // ~214 MB
  const size_t TB = BASE + DH * 2 + (size_t)2048 * 4096 * 2;       // ~37.9 MB

  char* ws = (char*)d_ws;
  float* P = (float*)ws;
  float* accb = (float*)(ws + (64 << 10));
  __bf16* xb = (__bf16*)(ws + (64 << 10) + (size_t)2048 * 1024 * 4);
  char* ws2 = ws + BASE;

  if (ws_size >= TA) {
    router_kernel<<<512, 256, 0, stream>>>(x, rw, rb, P, probs_out);
    hipMemsetAsync(accb, 0, (size_t)2048 * 1024 * 4, stream);
    cvt_kernel<<<1024, 256, 0, stream>>>(x, xb);
    __bf16* WT = (__bf16*)ws2;      // 64 MB: W1T, then reused as W2T
    __bf16* Hs = WT + 8 * DH;       // [2048][32768] bf16
    transconv_kernel<<<dim3(4, 64, 8), 256, 0, stream>>>(
        w1, WT, 1024, 4096, 64, 1024, DH);
    gemm1_kernel<<<dim3(16, 32, 8), 256, 0, stream>>>(xb, WT, b1, P, Hs,
                                                      32768, 0, DH);
    transconv_kernel<<<dim3(16, 16, 8), 256, 0, stream>>>(
        w2, WT, 4096, 1024, 64, 32768, 4096);
    gemm2_kernel<<<dim3(16, 8, 8), 256, 0, stream>>>(Hs, WT, accb, 32768,
                                                     32768, 4096);
    finalize_kernel<<<2048, 256, 0, stream>>>(accb, P, b2, y);
  } else if (ws_size >= TB) {
    router_kernel<<<512, 256, 0, stream>>>(x, rw, rb, P, probs_out);
    hipMemsetAsync(accb, 0, (size_t)2048 * 1024 * 4, stream);
    cvt_kernel<<<1024, 256, 0, stream>>>(x, xb);
    __bf16* WT = (__bf16*)ws2;      // 8 MB
    __bf16* HsE = WT + DH;          // 16 MB
    for (int e = 0; e < 8; ++e) {
      transconv_kernel<<<dim3(4, 64, 1), 256, 0, stream>>>(
          w1 + e * DH, WT, 1024, 4096, 64, 1024, 0);
      gemm1_kernel<<<dim3(16, 32, 1), 256, 0, stream>>>(xb, WT, b1, P, HsE,
                                                        4096, e, 0);
      transconv_kernel<<<dim3(16, 16, 1), 256, 0, stream>>>(
          w2 + e * DH, WT, 4096, 1024, 64, 4096, 0);
      gemm2_kernel<<<dim3(16, 8, 1), 256, 0, stream>>>(HsE, WT, accb, 4096,
                                                       4096, 0);
    }
    finalize_kernel<<<2048, 256, 0, stream>>>(accb, P, b2, y);
  } else {
    router_kernel<<<512, 256, 0, stream>>>(x, rw, rb, (float*)nullptr,
                                           probs_out);
    fused_naive_kernel<<<256, 256, 0, stream>>>(x, w1, b1, w2, b2, probs_out,
                                                y);
  }
}